// Round 4
// baseline (74.830 us; speedup 1.0000x reference)
//
#include <hip/hip_runtime.h>

#define NPED 4096
#define NBLK 512
#define BI 256
#define GPB 8               // pedestrians (i's) per block
#define EPSF 1e-8f
#define DTF 0.4f
#define INV_MASS (1.0f/60.0f)
// mag = 10 * exp((0.6 - dist)/0.71) = exp2( C0 + C1*dist )
#define C1f (-2.0319648463225964f)   // -log2(e)/0.71
#define C0f (4.54110700268092f)      // log2(10) + 0.6*log2(e)/0.71
#define NLOG2E (-1.4426950408889634f)

__device__ __forceinline__ float rsqf(float x) { return __builtin_amdgcn_rsqf(x); }
__device__ __forceinline__ float ex2(float x)  { return __builtin_amdgcn_exp2f(x); }

// integrate one pedestrian given summed repulsion (fx,fy)
__device__ __forceinline__ float4 integrate_one(float4 st, float2 g,
                                                float fx, float fy) {
    fx *= INV_MASS; fy *= INV_MASS;          // rf
    float tx = g.x - st.x, ty = g.y - st.y;
    float invg = rsqf(fmaf(tx, tx, fmaf(ty, ty, EPSF)));
    float Fx = fx + 2.f * fmaf(tx, invg, -st.z);   // rf + af
    float Fy = fy + 2.f * fmaf(ty, invg, -st.w);
    float npx = fmaf(0.08f, Fx, fmaf(DTF, st.z, st.x));  // 0.5*DT^2
    float npy = fmaf(0.08f, Fy, fmaf(DTF, st.w, st.y));
    float nvx = fmaf(DTF, Fx, st.z);
    float nvy = fmaf(DTF, Fy, st.w);
    float invs = rsqf(fmaf(nvx, nvx, fmaf(nvy, nvy, EPSF)));
    float sc = fminf(1.f, invs);             // min(1, PED_SPEED/spd)
    return make_float4(npx, npy, nvx * sc, nvy * sc);
}

__global__ __launch_bounds__(BI) void fused_kernel(const float4* __restrict__ state,
                                                   const float* __restrict__ cost_in,
                                                   const float4* __restrict__ stk,
                                                   const float2* __restrict__ goal,
                                                   const float* __restrict__ obs,
                                                   float* __restrict__ out) {
    __shared__ float2 spos[NPED];   // 32 KB: all positions
    __shared__ float2 npos[GPB];    // new poses of my 8 peds
    __shared__ float  rsum[8];      // 4 waves x (rfx,rfy)
    __shared__ float2 rpose;        // robot new pose
    const int t = threadIdx.x, b = blockIdx.x;

    // stage all 4096 positions (coalesced float4 reads)
    #pragma unroll
    for (int k = 0; k < NPED / BI; ++k) {
        float4 r = state[k * BI + t];
        spos[k * BI + t] = make_float2(r.x, r.y);
    }
    __syncthreads();

    const int g = t >> 5, l = t & 31;
    const int i = b * GPB + g;        // my pedestrian
    const float2 me = spos[i];        // broadcast read

    // ---- full repulsion force on pedestrian i (32 lanes split 4096 j's) ----
    float fx = 0.f, fy = 0.f;
    #pragma unroll 8
    for (int k = 0; k < NPED / 32; ++k) {
        float2 pj = spos[k * 32 + l];   // wave: 32 distinct addrs, 2x broadcast
        float dx = me.x - pj.x;
        float dy = me.y - pj.y;
        float d2 = fmaf(dx, dx, fmaf(dy, dy, EPSF));
        float inv = rsqf(d2);                        // 1/dist
        float dist = d2 * inv;
        float w = ex2(fmaf(dist, C1f, C0f)) * inv;   // mag/dist
        fx = fmaf(w, dx, fx);                        // j==i -> exactly 0
        fy = fmaf(w, dy, fy);
    }

    // ---- redundant robot (i=0) force: 256 threads split 4096 j's ----
    float rfx = 0.f, rfy = 0.f;
    {
        const float2 r0 = spos[0];
        #pragma unroll
        for (int k = 0; k < NPED / BI; ++k) {
            float2 pj = spos[k * BI + t];
            float dx = r0.x - pj.x;
            float dy = r0.y - pj.y;
            float d2 = fmaf(dx, dx, fmaf(dy, dy, EPSF));
            float inv = rsqf(d2);
            float dist = d2 * inv;
            float w = ex2(fmaf(dist, C1f, C0f)) * inv;
            rfx = fmaf(w, dx, rfx);
            rfy = fmaf(w, dy, rfy);
        }
    }

    // group (32-lane) reduction of (fx,fy)
    #pragma unroll
    for (int m = 16; m > 0; m >>= 1) {
        fx += __shfl_xor(fx, m);
        fy += __shfl_xor(fy, m);
    }
    // wave (64-lane) reduction of robot force, then LDS
    #pragma unroll
    for (int m = 32; m > 0; m >>= 1) {
        rfx += __shfl_xor(rfx, m);
        rfy += __shfl_xor(rfy, m);
    }
    if ((t & 63) == 0) { rsum[(t >> 6) * 2] = rfx; rsum[(t >> 6) * 2 + 1] = rfy; }
    __syncthreads();

    if (t == 0) {
        float Rx = rsum[0] + rsum[2] + rsum[4] + rsum[6];
        float Ry = rsum[1] + rsum[3] + rsum[5] + rsum[7];
        float4 rp = integrate_one(state[0], goal[0], Rx, Ry);
        rpose = make_float2(rp.x, rp.y);
    }
    // group leaders integrate their pedestrian
    if (l == 0) {
        float4 nw = integrate_one(state[i], goal[i], fx, fy);
        ((float4*)out)[i] = nw;
        npos[g] = make_float2(nw.x, nw.y);
    }
    // stacked = concat(stacked_in, state) at out offset N*4+1 (4B-aligned)
    if (t < 32) {
        int f = b * 32 + t;   // my block's 32-float slice of each region
        out[NPED * 4 + 1 + f]            = ((const float*)stk)[f];
        out[NPED * 4 + 1 + NPED * 4 + f] = ((const float*)state)[f];
    }
    __syncthreads();

    // ---- cost contribution of my 8 pedestrians ----
    if (t < GPB) {
        const int ii = b * GPB + t;
        float c = 0.f;
        if (ii >= 1) {
            float2 np = npos[t];
            float ox = obs[ii * 4 + 0], oy = obs[ii * 4 + 1];
            float dxo = np.x - ox, dyo = np.y - oy;
            float dev = sqrtf(fmaf(dxo, dxo, fmaf(dyo, dyo, EPSF)));
            float dxr = np.x - rpose.x, dyr = np.y - rpose.y;
            float d = sqrtf(fmaf(dxr, dxr, fmaf(dyr, dyr, EPSF)));
            float blame = ex2(NLOG2E * d);          // exp(-d)
            c = fmaf(5.f, dev, 2.f * blame);
        }
        #pragma unroll
        for (int m = 4; m > 0; m >>= 1) c += __shfl_xor(c, m);  // lanes 0..7
        if (t == 0) {
            float total = c;
            if (b == 0) {
                const float* gf = (const float*)goal;
                const float* sf = (const float*)state;
                float a1x = sf[0] - gf[0], a1y = sf[1] - gf[1];
                float a2x = rpose.x - gf[0], a2y = rpose.y - gf[1];
                float pg = sqrtf(fmaf(a1x, a1x, fmaf(a1y, a1y, EPSF)))
                         - sqrtf(fmaf(a2x, a2x, fmaf(a2y, a2y, EPSF)));
                total += cost_in[0] - pg;
            }
            atomicAdd(out + NPED * 4, total);  // poison residual -3e-13, negligible
        }
    }
}

extern "C" void kernel_launch(void* const* d_in, const int* in_sizes, int n_in,
                              void* d_out, int out_size, void* d_ws, size_t ws_size,
                              hipStream_t stream) {
    const float4* state = (const float4*)d_in[0];   // (N,4)
    const float*  cost  = (const float*)d_in[1];    // (1,)
    const float4* stk   = (const float4*)d_in[2];   // (N,4)
    const float2* goal  = (const float2*)d_in[3];   // (N,2)
    const float*  obs   = (const float*)d_in[4];    // (N,4)
    float* out = (float*)d_out;                     // N*4 | 1 | 2N*4

    fused_kernel<<<dim3(NBLK), BI, 0, stream>>>(state, cost, stk, goal, obs, out);
}

// Round 5
// 72.728 us; speedup vs baseline: 1.0289x; 1.0289x over previous
//
#include <hip/hip_runtime.h>

#define NPED 4096
#define SPLIT 32            // j-dimension splits
#define JC (NPED / SPLIT)   // 128 j's per chunk
#define BI 256              // threads per block
#define EPSF 1e-8f
#define DTF 0.4f
#define INV_MASS (1.0f/60.0f)
// mag = 10 * exp((0.6 - dist)/0.71) = exp2( C0 + C1*dist )
#define C1f (-2.0319648463225964f)   // -log2(e)/0.71
#define C0f (4.54110700268092f)      // log2(10) + 0.6*log2(e)/0.71
#define NLOG2E (-1.4426950408889634f)

typedef float f2 __attribute__((ext_vector_type(2)));  // lowers to v_pk_* on gfx950

__device__ __forceinline__ float rsqf(float x) { return __builtin_amdgcn_rsqf(x); }
__device__ __forceinline__ float ex2(float x)  { return __builtin_amdgcn_exp2f(x); }

// ---- Kernel A: O(N^2) pairwise repulsion partials; seeds the cost cell ----
__global__ __launch_bounds__(BI) void forces_kernel(const float4* __restrict__ state,
                                                    const float* __restrict__ cost_in,
                                                    f2* __restrict__ part,
                                                    float* __restrict__ out) {
    __shared__ f2 spos[JC];
    const int t  = threadIdx.x;
    const int ib = blockIdx.x & 15;   // i-block 0..15
    const int s  = blockIdx.x >> 4;   // j-split 0..31
    if (t < JC) {
        float4 r = state[s * JC + t];
        spos[t] = (f2){r.x, r.y};
    }
    if (blockIdx.x == 0 && t == 0) out[NPED * 4] = cost_in[0];  // seed cost
    const int i = ib * BI + t;
    float4 mest = state[i];
    __syncthreads();
    const f2 me = {mest.x, mest.y};
    f2 acc = {0.f, 0.f};
    #pragma unroll 8
    for (int j = 0; j < JC; ++j) {
        f2 d = me - spos[j];                         // v_pk_add (neg)
        float d2 = fmaf(d.x, d.x, fmaf(d.y, d.y, EPSF));
        float inv = rsqf(d2);                        // 1/dist
        float dist = d2 * inv;
        float w = ex2(fmaf(dist, C1f, C0f)) * inv;   // mag/dist
        acc = d * w + acc;                           // v_pk_fma; j==i -> exactly 0
    }
    part[s * NPED + i] = acc;
}

// integrate one pedestrian given summed repulsion (fx,fy)
__device__ __forceinline__ float4 integrate_one(float4 st, float2 g,
                                                float fx, float fy) {
    fx *= INV_MASS; fy *= INV_MASS;          // rf
    float tx = g.x - st.x, ty = g.y - st.y;
    float invg = rsqf(fmaf(tx, tx, fmaf(ty, ty, EPSF)));
    float Fx = fx + 2.f * fmaf(tx, invg, -st.z);   // rf + af
    float Fy = fy + 2.f * fmaf(ty, invg, -st.w);
    float npx = fmaf(0.08f, Fx, fmaf(DTF, st.z, st.x));  // 0.5*DT^2 = 0.08
    float npy = fmaf(0.08f, Fy, fmaf(DTF, st.w, st.y));
    float nvx = fmaf(DTF, Fx, st.z);
    float nvy = fmaf(DTF, Fy, st.w);
    float invs = rsqf(fmaf(nvx, nvx, fmaf(nvy, nvy, EPSF)));
    float sc = fminf(1.f, invs);             // min(1, PED_SPEED/spd)
    return make_float4(npx, npy, nvx * sc, nvy * sc);
}

// ---- Kernel B: reduce + integrate + write out/stacked + cost (atomic) ----
__global__ __launch_bounds__(BI) void finish_kernel(const float4* __restrict__ state,
                                                    const float2* __restrict__ goal,
                                                    const float4* __restrict__ stk,
                                                    const float* __restrict__ obs,
                                                    const f2* __restrict__ part,
                                                    float* __restrict__ out) {
    const int t  = threadIdx.x;
    const int b  = blockIdx.x;     // 0..15
    const int ii = b * BI + t;

    // --- integrate my pedestrian ---
    f2 f = {0.f, 0.f};
    #pragma unroll
    for (int sp = 0; sp < SPLIT; ++sp) f += part[sp * NPED + ii];
    float4 st = state[ii];
    float4 nw = integrate_one(st, goal[ii], f.x, f.y);
    ((float4*)out)[ii] = nw;

    // stacked = concat(stacked_in, state) at out offset N*4+1 (4B-aligned)
    float4 sv = stk[ii];
    float* o1 = out + (NPED * 4 + 1) + ii * 4;
    o1[0] = sv.x; o1[1] = sv.y; o1[2] = sv.z; o1[3] = sv.w;
    float* o2 = o1 + NPED * 4;
    o2[0] = st.x; o2[1] = st.y; o2[2] = st.z; o2[3] = st.w;

    // --- robot new pose, computed redundantly in every block (wave 0) ---
    __shared__ float2 rpose;
    if (t < 64) {
        f2 rf = {0.f, 0.f};
        if (t < SPLIT) rf = part[t * NPED];
        #pragma unroll
        for (int off = 16; off > 0; off >>= 1) {
            rf.x += __shfl_down(rf.x, off);
            rf.y += __shfl_down(rf.y, off);
        }
        if (t == 0) {
            float4 r0 = integrate_one(state[0], goal[0], rf.x, rf.y);
            rpose = make_float2(r0.x, r0.y);
        }
    }
    __syncthreads();
    const float rx = rpose.x, ry = rpose.y;

    // --- dev/blame contribution for my pedestrian (skip robot ii==0) ---
    float c = 0.f;
    if (ii >= 1) {
        float ox = obs[ii * 4 + 0], oy = obs[ii * 4 + 1];
        float dxo = nw.x - ox, dyo = nw.y - oy;
        float dev = sqrtf(fmaf(dxo, dxo, fmaf(dyo, dyo, EPSF)));
        float dxr = nw.x - rx, dyr = nw.y - ry;
        float d = sqrtf(fmaf(dxr, dxr, fmaf(dyr, dyr, EPSF)));
        float blame = ex2(NLOG2E * d);          // exp(-d)
        c = fmaf(5.f, dev, 2.f * blame);        // A_COST*dev + B_COST*blame
    }
    #pragma unroll
    for (int off = 32; off > 0; off >>= 1) c += __shfl_down(c, off);
    __shared__ float sc4[4];
    if ((t & 63) == 0) sc4[t >> 6] = c;
    __syncthreads();
    if (t == 0) {
        float total = sc4[0] + sc4[1] + sc4[2] + sc4[3];
        if (b == 0) {
            const float* stf = (const float*)state;
            const float* gf  = (const float*)goal;
            float gx = gf[0], gy = gf[1];
            float a1x = stf[0] - gx, a1y = stf[1] - gy;
            float a2x = rx - gx,     a2y = ry - gy;
            float pg = sqrtf(fmaf(a1x, a1x, fmaf(a1y, a1y, EPSF)))
                     - sqrtf(fmaf(a2x, a2x, fmaf(a2y, a2y, EPSF)));
            total -= pg;
        }
        atomicAdd(out + NPED * 4, total);
    }
}

extern "C" void kernel_launch(void* const* d_in, const int* in_sizes, int n_in,
                              void* d_out, int out_size, void* d_ws, size_t ws_size,
                              hipStream_t stream) {
    const float4* state = (const float4*)d_in[0];   // (N,4)
    const float*  cost  = (const float*)d_in[1];    // (1,)
    const float4* stk   = (const float4*)d_in[2];   // (N,4)
    const float2* goal  = (const float2*)d_in[3];   // (N,2)
    const float*  obs   = (const float*)d_in[4];    // (N,4)
    float* out = (float*)d_out;                     // N*4 | 1 | 2N*4
    f2* part = (f2*)d_ws;                           // SPLIT*N f2 = 1 MiB

    forces_kernel<<<dim3(16 * SPLIT), BI, 0, stream>>>(state, cost, part, out);
    finish_kernel<<<dim3(16), BI, 0, stream>>>(state, goal, stk, obs, part, out);
}